// Round 2
// baseline (587.724 us; speedup 1.0000x reference)
//
#include <hip/hip_runtime.h>
#include <hip/hip_bf16.h>

#define NHEAD 16
#define HDIM 64
#define DINNER 1024
#define NBATCH 4
#define SEQ 2048
#define NTOK (NBATCH*SEQ)   // 8192

typedef __bf16 bf16;
typedef __bf16 bf16x8 __attribute__((ext_vector_type(8)));
typedef float f32x4 __attribute__((ext_vector_type(4)));

// workspace layout (bf16 element offsets); ~68.7 MB total
// byte 0..3: dtype flag (1 = inputs are bf16, 0 = fp32)
#define OFF_BO   8
#define OFF_XB   128
#define OFF_WQT  (OFF_XB + NTOK*HDIM)
#define OFF_WKT  (OFF_WQT + DINNER*HDIM)
#define OFF_WVT  (OFF_WKT + DINNER*HDIM)
#define OFF_WOT  (OFF_WVT + DINNER*HDIM)
#define OFF_Q    (OFF_WOT + DINNER*HDIM)
#define OFF_K    (OFF_Q + NTOK*DINNER)
#define OFF_VT   (OFF_K + NTOK*DINNER)
#define OFF_ATT  (OFF_VT + NTOK*DINNER)

static __device__ __forceinline__ bf16x8 ld8(const bf16* p) {
  return *reinterpret_cast<const bf16x8*>(p);
}

// ---------------- kernel 0: runtime input-dtype detection ------------------
// bf16 N(0,1) data: every uint16's exponent field in [64,140]. fp32 data:
// even uint16s are random mantissa bits -> ~uniform exponents -> test fails.
__global__ __launch_bounds__(64) void detect_kernel(const unsigned short* __restrict__ xb,
                                                    int* __restrict__ flag) {
  int lane = threadIdx.x;
  bool ok = true;
  for (int i = 0; i < 8; i++) {
    unsigned e = (xb[lane * 8 + i] >> 7) & 0xFF;
    ok = ok && (e >= 64 && e <= 140);
  }
  unsigned long long m = __ballot(ok);
  if (lane == 0) *flag = (m == ~0ull) ? 1 : 0;
}

// ---------------- kernel 1: normalize inputs into ws (bf16) ----------------
// z<3: W[64][1024]->WT[1024][64]; z==3: Wo->WoT[64][1024]; z=4..11: x copy;
// z==12: bo
__global__ __launch_bounds__(256) void prep_kernel(
    const void* __restrict__ x, const void* __restrict__ Wq,
    const void* __restrict__ Wk, const void* __restrict__ Wv,
    const void* __restrict__ Wo, const void* __restrict__ bo,
    const int* __restrict__ flag, bf16* __restrict__ ws) {
  int isbf = *flag;
  int z = blockIdx.y;
  int idx = blockIdx.x * 256 + threadIdx.x;   // 0..65535
  if (z < 3) {
    const void* src = (z == 0) ? Wq : (z == 1) ? Wk : Wv;
    bf16* dst = ws + ((z == 0) ? OFF_WQT : (z == 1) ? OFF_WKT : OFF_WVT);
    int n = idx >> 6, d = idx & 63;
    int i = d * DINNER + n;
    dst[n * HDIM + d] = isbf ? ((const bf16*)src)[i] : (bf16)((const float*)src)[i];
  } else if (z == 3) {
    int n = idx >> 10, k = idx & 1023;
    int i = k * HDIM + n;
    ws[OFF_WOT + n * DINNER + k] = isbf ? ((const bf16*)Wo)[i] : (bf16)((const float*)Wo)[i];
  } else if (z < 12) {
    int i = (z - 4) * 65536 + idx;
    ws[OFF_XB + i] = isbf ? ((const bf16*)x)[i] : (bf16)((const float*)x)[i];
  } else {
    if (idx < 64) ws[OFF_BO + idx] = isbf ? ((const bf16*)bo)[idx] : (bf16)((const float*)bo)[idx];
  }
}

// ---------------- kernel 2: fused QKV projection --------------------------
// xb[8192,64] @ W[64,1024] -> Q,K as [B,H,S,D]; V transposed as [B,H,D,S]
__global__ __launch_bounds__(64) void qkv_kernel(bf16* __restrict__ ws) {
  int tt = blockIdx.x, nc = blockIdx.y, pz = blockIdx.z;
  int lane = threadIdx.x;
  int lq = lane & 15, quad = lane >> 4;
  const bf16* WT = ws + OFF_WQT + pz * (DINNER * HDIM);  // [1024][64]
  int t0 = tt * 16;
  const bf16* xrow = ws + OFF_XB + (t0 + lq) * HDIM;
  bf16x8 a0 = ld8(xrow + quad * 8);
  bf16x8 a1 = ld8(xrow + 32 + quad * 8);
  int n0 = nc * 64;
  f32x4 acc[4];
#pragma unroll
  for (int c = 0; c < 4; c++) {
    const bf16* wr = WT + (n0 + c * 16 + lq) * HDIM;
    bf16x8 b0 = ld8(wr + quad * 8);
    bf16x8 b1 = ld8(wr + 32 + quad * 8);
    f32x4 z = {0.f, 0.f, 0.f, 0.f};
    z = __builtin_amdgcn_mfma_f32_16x16x32_bf16(a0, b0, z, 0, 0, 0);
    z = __builtin_amdgcn_mfma_f32_16x16x32_bf16(a1, b1, z, 0, 0, 0);
    acc[c] = z;
  }
  bf16* Qb = ws + OFF_Q;
  bf16* Kb = ws + OFF_K;
  bf16* VTb = ws + OFF_VT;
#pragma unroll
  for (int c = 0; c < 4; c++) {
    int n = n0 + c * 16 + lq;
    int h = n >> 6, d = n & 63;
#pragma unroll
    for (int r = 0; r < 4; r++) {
      int t = t0 + quad * 4 + r;
      int b = t >> 11, s = t & (SEQ - 1);
      bf16 v = (bf16)acc[c][r];
      if (pz == 0)      Qb[((b * NHEAD + h) * SEQ + s) * HDIM + d] = v;
      else if (pz == 1) Kb[((b * NHEAD + h) * SEQ + s) * HDIM + d] = v;
      else              VTb[((b * NHEAD + h) * HDIM + d) * SEQ + s] = v;
    }
  }
}

// ---------------- kernel 3: flash attention -------------------------------
// grid (S/64, B*H), block 256 (4 waves; wave w owns q-rows qb+16w..+15)
__global__ __launch_bounds__(256) void flash_kernel(const int* __restrict__ cmask,
                                                    bf16* __restrict__ ws) {
  __shared__ __align__(16) bf16 Pl[4][16 * 32];
  int qt = blockIdx.x, bh = blockIdx.y;
  int w = threadIdx.x >> 6;
  int lane = threadIdx.x & 63;
  int lq = lane & 15, quad = lane >> 4;
  int causal = cmask[0];
  const bf16* Q = ws + OFF_Q + (size_t)bh * SEQ * HDIM;
  const bf16* K = ws + OFF_K + (size_t)bh * SEQ * HDIM;
  const bf16* VT = ws + OFF_VT + (size_t)bh * HDIM * SEQ;
  int qb = qt * 64;
  int qw = qb + w * 16;

  const bf16* qrow = Q + (qw + lq) * HDIM;
  bf16x8 aq0 = ld8(qrow + quad * 8);
  bf16x8 aq1 = ld8(qrow + 32 + quad * 8);

  f32x4 o[4] = {{0.f,0.f,0.f,0.f},{0.f,0.f,0.f,0.f},{0.f,0.f,0.f,0.f},{0.f,0.f,0.f,0.f}};
  float m[4], l[4];
#pragma unroll
  for (int r = 0; r < 4; r++) { m[r] = -__builtin_inff(); l[r] = 0.f; }

  int kend = causal ? (qb + 63) : (SEQ - 1);   // block-uniform (barrier-safe)
  for (int k0 = 0; k0 <= kend; k0 += 32) {
    bool active = (!causal) || (k0 <= qw + 15);  // wave-uniform
    if (active) {
      const bf16* kr0 = K + (k0 + lq) * HDIM;
      const bf16* kr1 = K + (k0 + 16 + lq) * HDIM;
      f32x4 s0 = {0.f,0.f,0.f,0.f}, s1 = {0.f,0.f,0.f,0.f};
      s0 = __builtin_amdgcn_mfma_f32_16x16x32_bf16(aq0, ld8(kr0 + quad * 8), s0, 0,0,0);
      s0 = __builtin_amdgcn_mfma_f32_16x16x32_bf16(aq1, ld8(kr0 + 32 + quad * 8), s0, 0,0,0);
      s1 = __builtin_amdgcn_mfma_f32_16x16x32_bf16(aq0, ld8(kr1 + quad * 8), s1, 0,0,0);
      s1 = __builtin_amdgcn_mfma_f32_16x16x32_bf16(aq1, ld8(kr1 + 32 + quad * 8), s1, 0,0,0);
      float alr[4];
#pragma unroll
      for (int r = 0; r < 4; r++) {
        int q = qw + quad * 4 + r;
        float v0 = s0[r] * 0.125f;
        float v1 = s1[r] * 0.125f;
        if (causal) {
          if (k0 + lq > q)      v0 = -1e9f;
          if (k0 + 16 + lq > q) v1 = -1e9f;
        }
        float mx = fmaxf(v0, v1);
#pragma unroll
        for (int off = 1; off < 16; off <<= 1) mx = fmaxf(mx, __shfl_xor(mx, off));
        float mn = fmaxf(m[r], mx);
        // fminf(.,0) is an exact no-op on sane data; suppresses NaN from inf-inf
        float al = __expf(fminf(m[r] - mn, 0.f));
        float e0 = __expf(fminf(v0 - mn, 0.f));
        float e1 = __expf(fminf(v1 - mn, 0.f));
        float sum = e0 + e1;
#pragma unroll
        for (int off = 1; off < 16; off <<= 1) sum += __shfl_xor(sum, off);
        l[r] = l[r] * al + sum;
        m[r] = mn;
        alr[r] = al;
        int row = quad * 4 + r;
        Pl[w][row * 32 + lq] = (bf16)e0;
        Pl[w][row * 32 + 16 + lq] = (bf16)e1;
      }
#pragma unroll
      for (int c = 0; c < 4; c++) {
#pragma unroll
        for (int r = 0; r < 4; r++) o[c][r] *= alr[r];
      }
    }
    __syncthreads();
    if (active) {
      bf16x8 ap = ld8(&Pl[w][lq * 32 + quad * 8]);
#pragma unroll
      for (int c = 0; c < 4; c++) {
        const bf16* vr = VT + (c * 16 + lq) * SEQ + k0;
        bf16x8 bv = ld8(vr + quad * 8);
        o[c] = __builtin_amdgcn_mfma_f32_16x16x32_bf16(ap, bv, o[c], 0, 0, 0);
      }
    }
    __syncthreads();
  }
  bf16* ar = ws + OFF_ATT;
  int b = bh >> 4, h = bh & 15;
#pragma unroll
  for (int c = 0; c < 4; c++) {
#pragma unroll
    for (int r = 0; r < 4; r++) {
      int q = qw + quad * 4 + r;
      int d = c * 16 + lq;
      ar[((size_t)(b * SEQ + q)) * DINNER + h * HDIM + d] = (bf16)(o[c][r] / l[r]);
    }
  }
}

// ---------------- kernel 4: output projection + bias ----------------------
__global__ __launch_bounds__(64) void oproj_kernel(const bf16* __restrict__ ws,
                                                   const int* __restrict__ flag,
                                                   void* __restrict__ outp) {
  int isbf = *flag;
  int tt = blockIdx.x;
  int lane = threadIdx.x;
  int lq = lane & 15, quad = lane >> 4;
  const bf16* A = ws + OFF_ATT + (size_t)(tt * 16 + lq) * DINNER;
  const bf16* WoT = ws + OFF_WOT;   // [64][1024]
  f32x4 acc[4] = {{0.f,0.f,0.f,0.f},{0.f,0.f,0.f,0.f},{0.f,0.f,0.f,0.f},{0.f,0.f,0.f,0.f}};
  for (int k0 = 0; k0 < DINNER; k0 += 32) {
    bf16x8 a = ld8(A + k0 + quad * 8);
#pragma unroll
    for (int c = 0; c < 4; c++) {
      bf16x8 b = ld8(WoT + (size_t)(c * 16 + lq) * DINNER + k0 + quad * 8);
      acc[c] = __builtin_amdgcn_mfma_f32_16x16x32_bf16(a, b, acc[c], 0, 0, 0);
    }
  }
#pragma unroll
  for (int c = 0; c < 4; c++) {
    float bv = (float)ws[OFF_BO + c * 16 + lq];
#pragma unroll
    for (int r = 0; r < 4; r++) {
      int t = tt * 16 + quad * 4 + r;
      float v = acc[c][r] + bv;
      size_t o = (size_t)t * HDIM + c * 16 + lq;
      if (isbf) ((bf16*)outp)[o] = (bf16)v;
      else      ((float*)outp)[o] = v;
    }
  }
}

extern "C" void kernel_launch(void* const* d_in, const int* in_sizes, int n_in,
                              void* d_out, int out_size, void* d_ws, size_t ws_size,
                              hipStream_t stream) {
  const void* x  = d_in[0];
  const void* Wq = d_in[1];
  const void* Wk = d_in[2];
  const void* Wv = d_in[3];
  const void* Wo = d_in[4];
  const void* bo = d_in[5];
  const int* cm  = (const int*)d_in[6];
  bf16* ws = (bf16*)d_ws;
  int* flag = (int*)d_ws;

  hipLaunchKernelGGL(detect_kernel, dim3(1), dim3(64), 0, stream,
                     (const unsigned short*)x, flag);
  hipLaunchKernelGGL(prep_kernel, dim3(256, 13), dim3(256), 0, stream,
                     x, Wq, Wk, Wv, Wo, bo, flag, ws);
  hipLaunchKernelGGL(qkv_kernel, dim3(512, 16, 3), dim3(64), 0, stream, ws);
  hipLaunchKernelGGL(flash_kernel, dim3(SEQ / 64, NBATCH * NHEAD), dim3(256), 0,
                     stream, cm, ws);
  hipLaunchKernelGGL(oproj_kernel, dim3(512), dim3(64), 0, stream, ws, flag, d_out);
}

// Round 3
// 308.185 us; speedup vs baseline: 1.9070x; 1.9070x over previous
//
#include <hip/hip_runtime.h>
#include <hip/hip_bf16.h>

#define NHEAD 16
#define HDIM 64
#define DINNER 1024
#define NBATCH 4
#define SEQ 2048
#define NTOK (NBATCH*SEQ)   // 8192

typedef __bf16 bf16;
typedef __bf16 bf16x4 __attribute__((ext_vector_type(4)));
typedef __bf16 bf16x8 __attribute__((ext_vector_type(8)));
typedef float f32x4 __attribute__((ext_vector_type(4)));

// workspace layout (bf16 element offsets)
#define OFF_BO   8
#define OFF_XB   128
#define OFF_WQT  (OFF_XB + NTOK*HDIM)
#define OFF_WKT  (OFF_WQT + DINNER*HDIM)
#define OFF_WVT  (OFF_WKT + DINNER*HDIM)
#define OFF_WOT  (OFF_WVT + DINNER*HDIM)
#define OFF_Q    (OFF_WOT + DINNER*HDIM)
#define OFF_K    (OFF_Q + NTOK*DINNER)
#define OFF_VT   (OFF_K + NTOK*DINNER)
#define OFF_ATT  (OFF_VT + NTOK*DINNER)

// scores scale folded with log2(e): exp2((s/8)*log2 e) == exp(s/8)
#define SSCALE 0.18033688011112042f
#define MASKVAL (-3.0e8f)

static __device__ __forceinline__ bf16x8 ld8(const bf16* p) {
  return *reinterpret_cast<const bf16x8*>(p);
}

// ---------------- kernel 0: runtime input-dtype detection ------------------
__global__ __launch_bounds__(64) void detect_kernel(const unsigned short* __restrict__ xb,
                                                    int* __restrict__ flag) {
  int lane = threadIdx.x;
  bool ok = true;
  for (int i = 0; i < 8; i++) {
    unsigned e = (xb[lane * 8 + i] >> 7) & 0xFF;
    ok = ok && (e >= 64 && e <= 140);
  }
  unsigned long long m = __ballot(ok);
  if (lane == 0) *flag = (m == ~0ull) ? 1 : 0;
}

// ---------------- kernel 1: normalize inputs into ws (bf16) ----------------
__global__ __launch_bounds__(256) void prep_kernel(
    const void* __restrict__ x, const void* __restrict__ Wq,
    const void* __restrict__ Wk, const void* __restrict__ Wv,
    const void* __restrict__ Wo, const void* __restrict__ bo,
    const int* __restrict__ flag, bf16* __restrict__ ws) {
  int isbf = *flag;
  int z = blockIdx.y;
  int idx = blockIdx.x * 256 + threadIdx.x;
  if (z < 3) {
    const void* src = (z == 0) ? Wq : (z == 1) ? Wk : Wv;
    bf16* dst = ws + ((z == 0) ? OFF_WQT : (z == 1) ? OFF_WKT : OFF_WVT);
    int n = idx >> 6, d = idx & 63;
    int i = d * DINNER + n;
    dst[n * HDIM + d] = isbf ? ((const bf16*)src)[i] : (bf16)((const float*)src)[i];
  } else if (z == 3) {
    int n = idx >> 10, k = idx & 1023;
    int i = k * HDIM + n;
    ws[OFF_WOT + n * DINNER + k] = isbf ? ((const bf16*)Wo)[i] : (bf16)((const float*)Wo)[i];
  } else if (z < 12) {
    int i = (z - 4) * 65536 + idx;
    ws[OFF_XB + i] = isbf ? ((const bf16*)x)[i] : (bf16)((const float*)x)[i];
  } else {
    if (idx < 64) ws[OFF_BO + idx] = isbf ? ((const bf16*)bo)[idx] : (bf16)((const float*)bo)[idx];
  }
}

// ---------------- kernel 2: fused QKV projection (4 waves/block) -----------
__global__ __launch_bounds__(256) void qkv_kernel(bf16* __restrict__ ws) {
  int tt = blockIdx.x, pz = blockIdx.z;
  int nc = blockIdx.y * 4 + (threadIdx.x >> 6);
  int lane = threadIdx.x & 63;
  int lq = lane & 15, quad = lane >> 4;
  const bf16* WT = ws + OFF_WQT + pz * (DINNER * HDIM);
  int t0 = tt * 16;
  const bf16* xrow = ws + OFF_XB + (t0 + lq) * HDIM;
  bf16x8 a0 = ld8(xrow + quad * 8);
  bf16x8 a1 = ld8(xrow + 32 + quad * 8);
  int n0 = nc * 64;
  f32x4 acc[4];
#pragma unroll
  for (int c = 0; c < 4; c++) {
    const bf16* wr = WT + (n0 + c * 16 + lq) * HDIM;
    bf16x8 b0 = ld8(wr + quad * 8);
    bf16x8 b1 = ld8(wr + 32 + quad * 8);
    f32x4 z = {0.f, 0.f, 0.f, 0.f};
    z = __builtin_amdgcn_mfma_f32_16x16x32_bf16(a0, b0, z, 0, 0, 0);
    z = __builtin_amdgcn_mfma_f32_16x16x32_bf16(a1, b1, z, 0, 0, 0);
    acc[c] = z;
  }
  bf16* Qb = ws + OFF_Q;
  bf16* Kb = ws + OFF_K;
  bf16* VTb = ws + OFF_VT;
#pragma unroll
  for (int c = 0; c < 4; c++) {
    int n = n0 + c * 16 + lq;
    int h = n >> 6, d = n & 63;
#pragma unroll
    for (int r = 0; r < 4; r++) {
      int t = t0 + quad * 4 + r;
      int b = t >> 11, s = t & (SEQ - 1);
      bf16 v = (bf16)acc[c][r];
      if (pz == 0)      Qb[((b * NHEAD + h) * SEQ + s) * HDIM + d] = v;
      else if (pz == 1) Kb[((b * NHEAD + h) * SEQ + s) * HDIM + d] = v;
      else              VTb[((b * NHEAD + h) * HDIM + d) * SEQ + s] = v;
    }
  }
}

// ---------------- kernel 3: flash attention (barrier-free) -----------------
// grid (64 bh, 16 qt), block 256 = 4 independent waves; wave owns 32 q-rows.
// 64-key tiles; score group g covers key k0+4*lq+g so each lane's 4 P values
// are contiguous keys -> one ds_write_b64 per row (no LDS conflicts).
__global__ __launch_bounds__(256) void flash_kernel(const int* __restrict__ cmask,
                                                    bf16* __restrict__ ws) {
  __shared__ __align__(16) bf16 Pl[8 * 16 * 72];  // [(w*2+m)][row][72]
  int bh = blockIdx.x;
  int qt = 15 - blockIdx.y;               // longest q-tiles dispatched first
  int w = threadIdx.x >> 6;
  int lane = threadIdx.x & 63;
  int lq = lane & 15, quad = lane >> 4;
  int causal = cmask[0];
  const bf16* Q = ws + OFF_Q + (size_t)bh * SEQ * HDIM;
  const bf16* K = ws + OFF_K + (size_t)bh * SEQ * HDIM;
  const bf16* VT = ws + OFF_VT + (size_t)bh * HDIM * SEQ;
  int qw = qt * 128 + w * 32;             // queries qw..qw+31

  bf16x8 aq[2][2];
#pragma unroll
  for (int m = 0; m < 2; m++) {
    const bf16* qrow = Q + (qw + m * 16 + lq) * HDIM;
    aq[m][0] = ld8(qrow + quad * 8);
    aq[m][1] = ld8(qrow + 32 + quad * 8);
  }

  f32x4 o[2][4];
  float mm[2][4], ll[2][4];
#pragma unroll
  for (int m = 0; m < 2; m++)
#pragma unroll
    for (int r = 0; r < 4; r++) {
      mm[m][r] = -__builtin_inff(); ll[m][r] = 0.f;
      o[m][r] = (f32x4){0.f, 0.f, 0.f, 0.f};
    }

  int base0 = (w * 2) * 16 * 72, base1 = (w * 2 + 1) * 16 * 72;
  int kend = causal ? (qw + 31) : (SEQ - 1);
  for (int k0 = 0; k0 <= kend; k0 += 64) {
    // ---- scores^ 32q x 64k (key = k0 + 4*col + g)
    f32x4 s[2][4];
#pragma unroll
    for (int g = 0; g < 4; g++) {
      const bf16* kr = K + (k0 + 4 * lq + g) * HDIM;
      bf16x8 b0 = ld8(kr + quad * 8);
      bf16x8 b1 = ld8(kr + 32 + quad * 8);
      f32x4 z0 = {0.f,0.f,0.f,0.f}, z1 = {0.f,0.f,0.f,0.f};
      z0 = __builtin_amdgcn_mfma_f32_16x16x32_bf16(aq[0][0], b0, z0, 0,0,0);
      z0 = __builtin_amdgcn_mfma_f32_16x16x32_bf16(aq[0][1], b1, z0, 0,0,0);
      z1 = __builtin_amdgcn_mfma_f32_16x16x32_bf16(aq[1][0], b0, z1, 0,0,0);
      z1 = __builtin_amdgcn_mfma_f32_16x16x32_bf16(aq[1][1], b1, z1, 0,0,0);
      s[0][g] = z0; s[1][g] = z1;
    }
    bool needmask = causal && (k0 + 63 > qw);
    // ---- online softmax (exp2 domain), per 16-row block m
#pragma unroll
    for (int m = 0; m < 2; m++) {
      float alr[4];
      int base = m ? base1 : base0;
#pragma unroll
      for (int r = 0; r < 4; r++) {
        int q = qw + m * 16 + quad * 4 + r;
        float v0 = s[0 + 0][0][0]; // placeholder avoided; real code below
        float va = s[m][0][r] * SSCALE;
        float vb = s[m][1][r] * SSCALE;
        float vc = s[m][2][r] * SSCALE;
        float vd = s[m][3][r] * SSCALE;
        if (needmask) {
          int kb = k0 + 4 * lq;
          if (kb + 0 > q) va = MASKVAL;
          if (kb + 1 > q) vb = MASKVAL;
          if (kb + 2 > q) vc = MASKVAL;
          if (kb + 3 > q) vd = MASKVAL;
        }
        float mx = fmaxf(fmaxf(va, vb), fmaxf(vc, vd));
#pragma unroll
        for (int off = 1; off < 16; off <<= 1) mx = fmaxf(mx, __shfl_xor(mx, off));
        float mn = fmaxf(mm[m][r], mx);
        float al = exp2f(fminf(mm[m][r] - mn, 0.f));
        float ea = exp2f(fminf(va - mn, 0.f));
        float eb = exp2f(fminf(vb - mn, 0.f));
        float ec = exp2f(fminf(vc - mn, 0.f));
        float ed = exp2f(fminf(vd - mn, 0.f));
        float sum = (ea + eb) + (ec + ed);
#pragma unroll
        for (int off = 1; off < 16; off <<= 1) sum += __shfl_xor(sum, off);
        ll[m][r] = ll[m][r] * al + sum;
        mm[m][r] = mn;
        alr[r] = al;
        bf16x4 pk = {(bf16)ea, (bf16)eb, (bf16)ec, (bf16)ed};
        *reinterpret_cast<bf16x4*>(&Pl[base + (quad * 4 + r) * 72 + 4 * lq]) = pk;
      }
#pragma unroll
      for (int c = 0; c < 4; c++)
#pragma unroll
        for (int r = 0; r < 4; r++) o[m][c][r] *= alr[r];
    }
    // ---- P @ V  (A from per-wave LDS; intra-wave, no barrier needed)
    bf16x8 ap[2][2];
#pragma unroll
    for (int m = 0; m < 2; m++) {
      int base = m ? base1 : base0;
      ap[m][0] = ld8(&Pl[base + lq * 72 + quad * 8]);
      ap[m][1] = ld8(&Pl[base + lq * 72 + 32 + quad * 8]);
    }
#pragma unroll
    for (int c = 0; c < 4; c++) {
      const bf16* vr = VT + (c * 16 + lq) * SEQ + k0;
      bf16x8 bv0 = ld8(vr + quad * 8);
      bf16x8 bv1 = ld8(vr + 32 + quad * 8);
#pragma unroll
      for (int m = 0; m < 2; m++) {
        o[m][c] = __builtin_amdgcn_mfma_f32_16x16x32_bf16(ap[m][0], bv0, o[m][c], 0,0,0);
        o[m][c] = __builtin_amdgcn_mfma_f32_16x16x32_bf16(ap[m][1], bv1, o[m][c], 0,0,0);
      }
    }
  }
  // ---- epilogue: normalize, write attn as [B,S,H*D]
  bf16* ar = ws + OFF_ATT;
  int b = bh >> 4, h = bh & 15;
#pragma unroll
  for (int m = 0; m < 2; m++) {
    float inv[4];
#pragma unroll
    for (int r = 0; r < 4; r++) inv[r] = 1.0f / ll[m][r];
#pragma unroll
    for (int c = 0; c < 4; c++)
#pragma unroll
      for (int r = 0; r < 4; r++) {
        int q = qw + m * 16 + quad * 4 + r;
        ar[((size_t)(b * SEQ + q)) * DINNER + h * HDIM + c * 16 + lq] =
            (bf16)(o[m][c][r] * inv[r]);
      }
  }
}

// ---------------- kernel 4: output projection, 4-wave split-K --------------
__global__ __launch_bounds__(256) void oproj_kernel(const bf16* __restrict__ ws,
                                                    const int* __restrict__ flag,
                                                    void* __restrict__ outp) {
  __shared__ __align__(16) float red[3 * 64 * 16];  // 12 KB
  int isbf = *flag;
  int tt = blockIdx.x;
  int w = threadIdx.x >> 6;
  int lane = threadIdx.x & 63;
  int lq = lane & 15, quad = lane >> 4;
  const bf16* A = ws + OFF_ATT + (size_t)(tt * 16 + lq) * DINNER;
  const bf16* WoT = ws + OFF_WOT;
  f32x4 acc[4];
#pragma unroll
  for (int c = 0; c < 4; c++) acc[c] = (f32x4){0.f, 0.f, 0.f, 0.f};
  int kbeg = w * 256;
  for (int k0 = kbeg; k0 < kbeg + 256; k0 += 32) {
    bf16x8 a = ld8(A + k0 + quad * 8);
#pragma unroll
    for (int c = 0; c < 4; c++) {
      bf16x8 b = ld8(WoT + (size_t)(c * 16 + lq) * DINNER + k0 + quad * 8);
      acc[c] = __builtin_amdgcn_mfma_f32_16x16x32_bf16(a, b, acc[c], 0, 0, 0);
    }
  }
  if (w > 0) {
#pragma unroll
    for (int c = 0; c < 4; c++)
      *reinterpret_cast<f32x4*>(&red[(((w - 1) * 64 + lane) * 4 + c) * 4]) = acc[c];
  }
  __syncthreads();
  if (w == 0) {
#pragma unroll
    for (int j = 0; j < 3; j++)
#pragma unroll
      for (int c = 0; c < 4; c++)
        acc[c] += *reinterpret_cast<f32x4*>(&red[((j * 64 + lane) * 4 + c) * 4]);
#pragma unroll
    for (int c = 0; c < 4; c++) {
      float bv = (float)ws[OFF_BO + c * 16 + lq];
#pragma unroll
      for (int r = 0; r < 4; r++) {
        int t = tt * 16 + quad * 4 + r;
        float v = acc[c][r] + bv;
        size_t oo = (size_t)t * HDIM + c * 16 + lq;
        if (isbf) ((bf16*)outp)[oo] = (bf16)v;
        else      ((float*)outp)[oo] = v;
      }
    }
  }
}

extern "C" void kernel_launch(void* const* d_in, const int* in_sizes, int n_in,
                              void* d_out, int out_size, void* d_ws, size_t ws_size,
                              hipStream_t stream) {
  const void* x  = d_in[0];
  const void* Wq = d_in[1];
  const void* Wk = d_in[2];
  const void* Wv = d_in[3];
  const void* Wo = d_in[4];
  const void* bo = d_in[5];
  const int* cm  = (const int*)d_in[6];
  bf16* ws = (bf16*)d_ws;
  int* flag = (int*)d_ws;

  hipLaunchKernelGGL(detect_kernel, dim3(1), dim3(64), 0, stream,
                     (const unsigned short*)x, flag);
  hipLaunchKernelGGL(prep_kernel, dim3(256, 13), dim3(256), 0, stream,
                     x, Wq, Wk, Wv, Wo, bo, flag, ws);
  hipLaunchKernelGGL(qkv_kernel, dim3(512, 4, 3), dim3(256), 0, stream, ws);
  hipLaunchKernelGGL(flash_kernel, dim3(64, 16), dim3(256), 0, stream, cm, ws);
  hipLaunchKernelGGL(oproj_kernel, dim3(512), dim3(256), 0, stream, ws, flag, d_out);
}

// Round 4
// 252.501 us; speedup vs baseline: 2.3276x; 1.2205x over previous
//
#include <hip/hip_runtime.h>
#include <hip/hip_bf16.h>

#define NHEAD 16
#define HDIM 64
#define DINNER 1024
#define NBATCH 4
#define SEQ 2048
#define NTOK (NBATCH*SEQ)   // 8192

typedef __bf16 bf16;
typedef __bf16 bf16x4 __attribute__((ext_vector_type(4)));
typedef __bf16 bf16x8 __attribute__((ext_vector_type(8)));
typedef float f32x4 __attribute__((ext_vector_type(4)));

// workspace layout (bf16 element offsets)
#define OFF_BO   8
#define OFF_XB   128
#define OFF_WQT  (OFF_XB + NTOK*HDIM)
#define OFF_WKT  (OFF_WQT + DINNER*HDIM)
#define OFF_WVT  (OFF_WKT + DINNER*HDIM)
#define OFF_WOT  (OFF_WVT + DINNER*HDIM)
#define OFF_Q    (OFF_WOT + DINNER*HDIM)
#define OFF_K    (OFF_Q + NTOK*DINNER)
#define OFF_VT   (OFF_K + NTOK*DINNER)
#define OFF_ATT  (OFF_VT + NTOK*DINNER)

// raw-score domain; exp2((s - m) * SSCALE) == exp((s - m)/8)
#define SSCALE 0.18033688011112042f
#define MASKVAL (-3.0e8f)

static __device__ __forceinline__ bf16x8 ld8(const bf16* p) {
  return *reinterpret_cast<const bf16x8*>(p);
}

// ---------------- kernel 0: runtime input-dtype detection ------------------
__global__ __launch_bounds__(64) void detect_kernel(const unsigned short* __restrict__ xb,
                                                    int* __restrict__ flag) {
  int lane = threadIdx.x;
  bool ok = true;
  for (int i = 0; i < 8; i++) {
    unsigned e = (xb[lane * 8 + i] >> 7) & 0xFF;
    ok = ok && (e >= 64 && e <= 140);
  }
  unsigned long long m = __ballot(ok);
  if (lane == 0) *flag = (m == ~0ull) ? 1 : 0;
}

// ---------------- kernel 1: normalize inputs into ws (bf16) ----------------
__global__ __launch_bounds__(256) void prep_kernel(
    const void* __restrict__ x, const void* __restrict__ Wq,
    const void* __restrict__ Wk, const void* __restrict__ Wv,
    const void* __restrict__ Wo, const void* __restrict__ bo,
    const int* __restrict__ flag, bf16* __restrict__ ws) {
  int isbf = *flag;
  int z = blockIdx.y;
  int idx = blockIdx.x * 256 + threadIdx.x;
  if (z < 3) {
    const void* src = (z == 0) ? Wq : (z == 1) ? Wk : Wv;
    bf16* dst = ws + ((z == 0) ? OFF_WQT : (z == 1) ? OFF_WKT : OFF_WVT);
    int n = idx >> 6, d = idx & 63;
    int i = d * DINNER + n;
    dst[n * HDIM + d] = isbf ? ((const bf16*)src)[i] : (bf16)((const float*)src)[i];
  } else if (z == 3) {
    int n = idx >> 10, k = idx & 1023;
    int i = k * HDIM + n;
    ws[OFF_WOT + n * DINNER + k] = isbf ? ((const bf16*)Wo)[i] : (bf16)((const float*)Wo)[i];
  } else if (z < 12) {
    int i = (z - 4) * 65536 + idx;
    ws[OFF_XB + i] = isbf ? ((const bf16*)x)[i] : (bf16)((const float*)x)[i];
  } else {
    if (idx < 64) ws[OFF_BO + idx] = isbf ? ((const bf16*)bo)[idx] : (bf16)((const float*)bo)[idx];
  }
}

// ---------------- kernel 2: fused QKV projection (4 waves/block) -----------
// pz<2: C[token][n] (A=x, B=W)  -> coalesced Q/K stores.
// pz==2: C[n][token] (A=W, B=x) -> token is the lane dim -> coalesced V^T.
__global__ __launch_bounds__(256) void qkv_kernel(bf16* __restrict__ ws) {
  int tt = blockIdx.x, pz = blockIdx.z;
  int nc = blockIdx.y * 4 + (threadIdx.x >> 6);
  int lane = threadIdx.x & 63;
  int lq = lane & 15, quad = lane >> 4;
  const bf16* WT = ws + OFF_WQT + pz * (DINNER * HDIM);
  int t0 = tt * 16;
  const bf16* xrow = ws + OFF_XB + (t0 + lq) * HDIM;
  bf16x8 x0 = ld8(xrow + quad * 8);
  bf16x8 x1 = ld8(xrow + 32 + quad * 8);
  int n0 = nc * 64;
  f32x4 acc[4];
  if (pz < 2) {
#pragma unroll
    for (int c = 0; c < 4; c++) {
      const bf16* wr = WT + (n0 + c * 16 + lq) * HDIM;
      f32x4 z = {0.f, 0.f, 0.f, 0.f};
      z = __builtin_amdgcn_mfma_f32_16x16x32_bf16(x0, ld8(wr + quad * 8), z, 0, 0, 0);
      z = __builtin_amdgcn_mfma_f32_16x16x32_bf16(x1, ld8(wr + 32 + quad * 8), z, 0, 0, 0);
      acc[c] = z;
    }
    bf16* P = ws + (pz == 0 ? OFF_Q : OFF_K);
#pragma unroll
    for (int c = 0; c < 4; c++) {
      int n = n0 + c * 16 + lq;
      int h = n >> 6, d = n & 63;
#pragma unroll
      for (int r = 0; r < 4; r++) {
        int t = t0 + quad * 4 + r;
        int b = t >> 11, s = t & (SEQ - 1);
        P[((b * NHEAD + h) * SEQ + s) * HDIM + d] = (bf16)acc[c][r];
      }
    }
  } else {
#pragma unroll
    for (int c = 0; c < 4; c++) {
      const bf16* wr = WT + (n0 + c * 16 + lq) * HDIM;
      f32x4 z = {0.f, 0.f, 0.f, 0.f};
      z = __builtin_amdgcn_mfma_f32_16x16x32_bf16(ld8(wr + quad * 8), x0, z, 0, 0, 0);
      z = __builtin_amdgcn_mfma_f32_16x16x32_bf16(ld8(wr + 32 + quad * 8), x1, z, 0, 0, 0);
      acc[c] = z;
    }
    bf16* VTb = ws + OFF_VT;
    int b = t0 >> 11, s0 = t0 & (SEQ - 1);
#pragma unroll
    for (int c = 0; c < 4; c++) {
#pragma unroll
      for (int r = 0; r < 4; r++) {
        int n = n0 + c * 16 + quad * 4 + r;
        int h = n >> 6, d = n & 63;
        VTb[(((size_t)b * NHEAD + h) * HDIM + d) * SEQ + s0 + lq] = (bf16)acc[c][r];
      }
    }
  }
}

// ---------------- kernel 3: flash attention, S^T orientation ---------------
// grid (64 bh, 16 qt), block 256 = 4 independent waves (no barriers).
// Wave owns 32 queries (2 col-groups of 16). Scores computed TRANSPOSED
// (row=key, col=query) so softmax reduces in-lane (15-op tree) + 2 shuffles.
__global__ __launch_bounds__(256) void flash_kernel(const int* __restrict__ cmask,
                                                    bf16* __restrict__ ws) {
  __shared__ __align__(16) bf16 Pl[8 * 16 * 72];  // [(w*2+m)][query][key pad72]
  int bh = blockIdx.x;
  int qt = 15 - blockIdx.y;               // longest q-tiles first
  int w = threadIdx.x >> 6;
  int lane = threadIdx.x & 63;
  int lq = lane & 15, quad = lane >> 4;
  int causal = cmask[0];
  const bf16* Q = ws + OFF_Q + (size_t)bh * SEQ * HDIM;
  const bf16* K = ws + OFF_K + (size_t)bh * SEQ * HDIM;
  const bf16* VT = ws + OFF_VT + (size_t)bh * HDIM * SEQ;
  int qw = qt * 128 + w * 32;             // queries qw..qw+31

  // Q as B-operand (cols=queries): same row loads as before
  bf16x8 bq[2][2];
#pragma unroll
  for (int m = 0; m < 2; m++) {
    const bf16* qrow = Q + (qw + m * 16 + lq) * HDIM;
    bq[m][0] = ld8(qrow + quad * 8);
    bq[m][1] = ld8(qrow + 32 + quad * 8);
  }

  f32x4 o[2][4];   // O^T: row=d (quad*4+r within c-subtile), col=query (lq)
  float mm[2], ll[2];
#pragma unroll
  for (int m = 0; m < 2; m++) {
    mm[m] = -__builtin_inff(); ll[m] = 0.f;
#pragma unroll
    for (int c = 0; c < 4; c++) o[m][c] = (f32x4){0.f, 0.f, 0.f, 0.f};
  }
  int base[2] = {(w * 2) * 16 * 72, (w * 2 + 1) * 16 * 72};

  int kend = causal ? (qw + 31) : (SEQ - 1);
  for (int k0 = 0; k0 <= kend; k0 += 64) {
    // K rows as A-operand (rows=keys), 4 subtiles of 16 keys
    bf16x8 ak0[4], ak1[4];
#pragma unroll
    for (int t = 0; t < 4; t++) {
      const bf16* kr = K + (k0 + t * 16 + lq) * HDIM;
      ak0[t] = ld8(kr + quad * 8);
      ak1[t] = ld8(kr + 32 + quad * 8);
    }
    // V^T rows as A-operand for PV (rows=d, k-dim=keys) — issue early
    bf16x8 av0[4], av1[4];
#pragma unroll
    for (int c = 0; c < 4; c++) {
      const bf16* vr = VT + (c * 16 + lq) * SEQ + k0;
      av0[c] = ld8(vr + quad * 8);
      av1[c] = ld8(vr + 32 + quad * 8);
    }
    // S^T tiles: st[m][t] rows=keys(t), cols=queries(m-group)
    f32x4 st[2][4];
#pragma unroll
    for (int m = 0; m < 2; m++)
#pragma unroll
      for (int t = 0; t < 4; t++) {
        f32x4 z = {0.f, 0.f, 0.f, 0.f};
        z = __builtin_amdgcn_mfma_f32_16x16x32_bf16(ak0[t], bq[m][0], z, 0, 0, 0);
        z = __builtin_amdgcn_mfma_f32_16x16x32_bf16(ak1[t], bq[m][1], z, 0, 0, 0);
        st[m][t] = z;
      }
    bool needmask = causal && (k0 + 63 > qw);
    float al2[2];
#pragma unroll
    for (int m = 0; m < 2; m++) {
      if (needmask) {
        int qrel = qw + m * 16 + lq - k0 - quad * 4;  // key t*16+r masked if > qrel
#pragma unroll
        for (int t = 0; t < 4; t++)
#pragma unroll
          for (int r = 0; r < 4; r++)
            if (t * 16 + r > qrel) st[m][t][r] = MASKVAL;
      }
      // in-lane max over 16 (ILP tree) + 2 cross-quad shuffles
      float x0 = fmaxf(fmaxf(st[m][0][0], st[m][0][1]), fmaxf(st[m][0][2], st[m][0][3]));
      float x1 = fmaxf(fmaxf(st[m][1][0], st[m][1][1]), fmaxf(st[m][1][2], st[m][1][3]));
      float x2 = fmaxf(fmaxf(st[m][2][0], st[m][2][1]), fmaxf(st[m][2][2], st[m][2][3]));
      float x3 = fmaxf(fmaxf(st[m][3][0], st[m][3][1]), fmaxf(st[m][3][2], st[m][3][3]));
      float mx = fmaxf(fmaxf(x0, x1), fmaxf(x2, x3));
      mx = fmaxf(mx, __shfl_xor(mx, 16));
      mx = fmaxf(mx, __shfl_xor(mx, 32));
      float mn = fmaxf(mm[m], mx);
      float al = exp2f((mm[m] - mn) * SSCALE);
      float mnS = mn * SSCALE;
      float e[4][4];
      float sum = 0.f;
#pragma unroll
      for (int t = 0; t < 4; t++) {
        float s0 = 0.f;
#pragma unroll
        for (int r = 0; r < 4; r++) {
          e[t][r] = exp2f(fmaf(st[m][t][r], SSCALE, -mnS));
          s0 += e[t][r];
        }
        sum += s0;
      }
      sum += __shfl_xor(sum, 16);
      sum += __shfl_xor(sum, 32);
      ll[m] = ll[m] * al + sum;
      mm[m] = mn;
      al2[m] = al;
#pragma unroll
      for (int t = 0; t < 4; t++) {
        bf16x4 pk = {(bf16)e[t][0], (bf16)e[t][1], (bf16)e[t][2], (bf16)e[t][3]};
        *reinterpret_cast<bf16x4*>(&Pl[base[m] + lq * 72 + t * 16 + quad * 4]) = pk;
      }
    }
#pragma unroll
    for (int m = 0; m < 2; m++)
#pragma unroll
      for (int c = 0; c < 4; c++)
#pragma unroll
        for (int r = 0; r < 4; r++) o[m][c][r] *= al2[m];
    // P^T as B-operand (cols=queries) from per-wave LDS
    bf16x8 bp[2][2];
#pragma unroll
    for (int m = 0; m < 2; m++) {
      bp[m][0] = ld8(&Pl[base[m] + lq * 72 + quad * 8]);
      bp[m][1] = ld8(&Pl[base[m] + lq * 72 + 32 + quad * 8]);
    }
#pragma unroll
    for (int c = 0; c < 4; c++)
#pragma unroll
      for (int m = 0; m < 2; m++) {
        o[m][c] = __builtin_amdgcn_mfma_f32_16x16x32_bf16(av0[c], bp[m][0], o[m][c], 0, 0, 0);
        o[m][c] = __builtin_amdgcn_mfma_f32_16x16x32_bf16(av1[c], bp[m][1], o[m][c], 0, 0, 0);
      }
  }
  // ---- epilogue: O^T -> attn[B,S,H*D]; d is the reg dim -> bf16x4 stores
  bf16* ar = ws + OFF_ATT;
  int b = bh >> 4, h = bh & 15;
#pragma unroll
  for (int m = 0; m < 2; m++) {
    float inv = 1.0f / ll[m];
    size_t rowoff = ((size_t)(b * SEQ + qw + m * 16 + lq)) * DINNER + h * HDIM;
#pragma unroll
    for (int c = 0; c < 4; c++) {
      bf16x4 ov = {(bf16)(o[m][c][0] * inv), (bf16)(o[m][c][1] * inv),
                   (bf16)(o[m][c][2] * inv), (bf16)(o[m][c][3] * inv)};
      *reinterpret_cast<bf16x4*>(&ar[rowoff + c * 16 + quad * 4]) = ov;
    }
  }
}

// ---------------- kernel 4: output projection, 4-wave split-K --------------
__global__ __launch_bounds__(256) void oproj_kernel(const bf16* __restrict__ ws,
                                                    const int* __restrict__ flag,
                                                    void* __restrict__ outp) {
  __shared__ __align__(16) float red[3 * 64 * 16];  // 12 KB
  int isbf = *flag;
  int tt = blockIdx.x;
  int w = threadIdx.x >> 6;
  int lane = threadIdx.x & 63;
  int lq = lane & 15, quad = lane >> 4;
  const bf16* A = ws + OFF_ATT + (size_t)(tt * 16 + lq) * DINNER;
  const bf16* WoT = ws + OFF_WOT;
  f32x4 acc[4];
#pragma unroll
  for (int c = 0; c < 4; c++) acc[c] = (f32x4){0.f, 0.f, 0.f, 0.f};
  int kbeg = w * 256;
  for (int k0 = kbeg; k0 < kbeg + 256; k0 += 32) {
    bf16x8 a = ld8(A + k0 + quad * 8);
#pragma unroll
    for (int c = 0; c < 4; c++) {
      bf16x8 b = ld8(WoT + (size_t)(c * 16 + lq) * DINNER + k0 + quad * 8);
      acc[c] = __builtin_amdgcn_mfma_f32_16x16x32_bf16(a, b, acc[c], 0, 0, 0);
    }
  }
  if (w > 0) {
#pragma unroll
    for (int c = 0; c < 4; c++)
      *reinterpret_cast<f32x4*>(&red[(((w - 1) * 64 + lane) * 4 + c) * 4]) = acc[c];
  }
  __syncthreads();
  if (w == 0) {
#pragma unroll
    for (int j = 0; j < 3; j++)
#pragma unroll
      for (int c = 0; c < 4; c++)
        acc[c] += *reinterpret_cast<f32x4*>(&red[((j * 64 + lane) * 4 + c) * 4]);
#pragma unroll
    for (int c = 0; c < 4; c++) {
      float bv = (float)ws[OFF_BO + c * 16 + lq];
#pragma unroll
      for (int r = 0; r < 4; r++) {
        int t = tt * 16 + quad * 4 + r;
        float v = acc[c][r] + bv;
        size_t oo = (size_t)t * HDIM + c * 16 + lq;
        if (isbf) ((bf16*)outp)[oo] = (bf16)v;
        else      ((float*)outp)[oo] = v;
      }
    }
  }
}

extern "C" void kernel_launch(void* const* d_in, const int* in_sizes, int n_in,
                              void* d_out, int out_size, void* d_ws, size_t ws_size,
                              hipStream_t stream) {
  const void* x  = d_in[0];
  const void* Wq = d_in[1];
  const void* Wk = d_in[2];
  const void* Wv = d_in[3];
  const void* Wo = d_in[4];
  const void* bo = d_in[5];
  const int* cm  = (const int*)d_in[6];
  bf16* ws = (bf16*)d_ws;
  int* flag = (int*)d_ws;

  hipLaunchKernelGGL(detect_kernel, dim3(1), dim3(64), 0, stream,
                     (const unsigned short*)x, flag);
  hipLaunchKernelGGL(prep_kernel, dim3(256, 13), dim3(256), 0, stream,
                     x, Wq, Wk, Wv, Wo, bo, flag, ws);
  hipLaunchKernelGGL(qkv_kernel, dim3(512, 4, 3), dim3(256), 0, stream, ws);
  hipLaunchKernelGGL(flash_kernel, dim3(64, 16), dim3(256), 0, stream, cm, ws);
  hipLaunchKernelGGL(oproj_kernel, dim3(512), dim3(256), 0, stream, ws, flag, d_out);
}

// Round 5
// 249.544 us; speedup vs baseline: 2.3552x; 1.0119x over previous
//
#include <hip/hip_runtime.h>
#include <hip/hip_bf16.h>

#define NHEAD 16
#define HDIM 64
#define DINNER 1024
#define NBATCH 4
#define SEQ 2048
#define NTOK (NBATCH*SEQ)   // 8192

typedef __bf16 bf16;
typedef __bf16 bf16x4 __attribute__((ext_vector_type(4)));
typedef __bf16 bf16x8 __attribute__((ext_vector_type(8)));
typedef float f32x4 __attribute__((ext_vector_type(4)));

// workspace layout (bf16 element offsets)
#define OFF_BO   8
#define OFF_XB   128
#define OFF_WQT  (OFF_XB + NTOK*HDIM)
#define OFF_WKT  (OFF_WQT + DINNER*HDIM)
#define OFF_WVT  (OFF_WKT + DINNER*HDIM)
#define OFF_WOT  (OFF_WVT + DINNER*HDIM)
#define OFF_Q    (OFF_WOT + DINNER*HDIM)
#define OFF_K    (OFF_Q + NTOK*DINNER)
#define OFF_VT   (OFF_K + NTOK*DINNER)
#define OFF_ATT  (OFF_VT + NTOK*DINNER)

// raw-score domain; exp2((s - m) * SSCALE) == exp((s - m)/8)
#define SSCALE 0.18033688011112042f
#define MASKVAL (-3.0e8f)

static __device__ __forceinline__ bf16x8 ld8(const bf16* p) {
  return *reinterpret_cast<const bf16x8*>(p);
}

// ---------------- kernel 0: runtime input-dtype detection ------------------
__global__ __launch_bounds__(64) void detect_kernel(const unsigned short* __restrict__ xb,
                                                    int* __restrict__ flag) {
  int lane = threadIdx.x;
  bool ok = true;
  for (int i = 0; i < 8; i++) {
    unsigned e = (xb[lane * 8 + i] >> 7) & 0xFF;
    ok = ok && (e >= 64 && e <= 140);
  }
  unsigned long long m = __ballot(ok);
  if (lane == 0) *flag = (m == ~0ull) ? 1 : 0;
}

// ---------------- kernel 1: normalize inputs into ws (bf16) ----------------
__global__ __launch_bounds__(256) void prep_kernel(
    const void* __restrict__ x, const void* __restrict__ Wq,
    const void* __restrict__ Wk, const void* __restrict__ Wv,
    const void* __restrict__ Wo, const void* __restrict__ bo,
    const int* __restrict__ flag, bf16* __restrict__ ws) {
  int isbf = *flag;
  int z = blockIdx.y;
  int idx = blockIdx.x * 256 + threadIdx.x;
  if (z < 3) {
    const void* src = (z == 0) ? Wq : (z == 1) ? Wk : Wv;
    bf16* dst = ws + ((z == 0) ? OFF_WQT : (z == 1) ? OFF_WKT : OFF_WVT);
    int n = idx >> 6, d = idx & 63;
    int i = d * DINNER + n;
    dst[n * HDIM + d] = isbf ? ((const bf16*)src)[i] : (bf16)((const float*)src)[i];
  } else if (z == 3) {
    int n = idx >> 10, k = idx & 1023;
    int i = k * HDIM + n;
    ws[OFF_WOT + n * DINNER + k] = isbf ? ((const bf16*)Wo)[i] : (bf16)((const float*)Wo)[i];
  } else if (z < 12) {
    int i = (z - 4) * 65536 + idx;
    ws[OFF_XB + i] = isbf ? ((const bf16*)x)[i] : (bf16)((const float*)x)[i];
  } else {
    if (idx < 64) ws[OFF_BO + idx] = isbf ? ((const bf16*)bo)[idx] : (bf16)((const float*)bo)[idx];
  }
}

// ---------------- kernel 2: fused QKV projection ---------------------------
// 64 tokens per wave (W-frags reused 4x). grid (128, 4, 3), block 256.
// pz<2: C[token][n] (A=x, B=W); pz==2: C[n][token] (A=W, B=x) -> V^T.
__global__ __launch_bounds__(256) void qkv_kernel(bf16* __restrict__ ws) {
  int tt = blockIdx.x, pz = blockIdx.z;
  int nc = blockIdx.y * 4 + (threadIdx.x >> 6);
  int lane = threadIdx.x & 63;
  int lq = lane & 15, quad = lane >> 4;
  const bf16* WT = ws + OFF_WQT + pz * (DINNER * HDIM);
  int n0 = nc * 64;
  bf16x8 w0[4], w1[4];
#pragma unroll
  for (int c = 0; c < 4; c++) {
    const bf16* wr = WT + (n0 + c * 16 + lq) * HDIM;
    w0[c] = ld8(wr + quad * 8);
    w1[c] = ld8(wr + 32 + quad * 8);
  }
  if (pz < 2) {
    bf16* P = ws + (pz == 0 ? OFF_Q : OFF_K);
#pragma unroll
    for (int mi = 0; mi < 4; mi++) {
      int t0 = tt * 64 + mi * 16;
      const bf16* xrow = ws + OFF_XB + (t0 + lq) * HDIM;
      bf16x8 x0 = ld8(xrow + quad * 8);
      bf16x8 x1 = ld8(xrow + 32 + quad * 8);
#pragma unroll
      for (int c = 0; c < 4; c++) {
        f32x4 z = {0.f, 0.f, 0.f, 0.f};
        z = __builtin_amdgcn_mfma_f32_16x16x32_bf16(x0, w0[c], z, 0, 0, 0);
        z = __builtin_amdgcn_mfma_f32_16x16x32_bf16(x1, w1[c], z, 0, 0, 0);
        int n = n0 + c * 16 + lq;
        int h = n >> 6, d = n & 63;
#pragma unroll
        for (int r = 0; r < 4; r++) {
          int t = t0 + quad * 4 + r;
          int b = t >> 11, s = t & (SEQ - 1);
          P[((b * NHEAD + h) * SEQ + s) * HDIM + d] = (bf16)z[r];
        }
      }
    }
  } else {
    bf16* VTb = ws + OFF_VT;
#pragma unroll
    for (int mi = 0; mi < 4; mi++) {
      int t0 = tt * 64 + mi * 16;
      const bf16* xrow = ws + OFF_XB + (t0 + lq) * HDIM;
      bf16x8 x0 = ld8(xrow + quad * 8);
      bf16x8 x1 = ld8(xrow + 32 + quad * 8);
      int b = t0 >> 11, s0 = t0 & (SEQ - 1);
#pragma unroll
      for (int c = 0; c < 4; c++) {
        f32x4 z = {0.f, 0.f, 0.f, 0.f};
        z = __builtin_amdgcn_mfma_f32_16x16x32_bf16(w0[c], x0, z, 0, 0, 0);
        z = __builtin_amdgcn_mfma_f32_16x16x32_bf16(w1[c], x1, z, 0, 0, 0);
#pragma unroll
        for (int r = 0; r < 4; r++) {
          int n = n0 + c * 16 + quad * 4 + r;
          int h = n >> 6, d = n & 63;
          VTb[(((size_t)b * NHEAD + h) * HDIM + d) * SEQ + s0 + lq] = (bf16)z[r];
        }
      }
    }
  }
}

// ---------------- kernel 3: flash attention, 1-wave blocks -----------------
// grid 4096 = 64 qi (longest first, fast axis... qi-major) x 64 bh.
// Wave owns 32 queries; S^T orientation (row=key, col=query): softmax is
// in-lane tree + 2 shuffles. All 4096 blocks co-resident at VGPR<=128.
__global__ __launch_bounds__(64, 4) void flash_kernel(const int* __restrict__ cmask,
                                                      bf16* __restrict__ ws) {
  __shared__ __align__(16) bf16 Pl[2 * 16 * 72];  // [m][query][key pad72]
  int bid = blockIdx.x;
  int bh = bid & 63;
  int qi = bid >> 6;
  int qw = (63 - qi) * 32;                // qi=0 dispatched first = longest
  int lane = threadIdx.x & 63;
  int lq = lane & 15, quad = lane >> 4;
  int causal = cmask[0];
  const bf16* Q = ws + OFF_Q + (size_t)bh * SEQ * HDIM;
  const bf16* K = ws + OFF_K + (size_t)bh * SEQ * HDIM;
  const bf16* VT = ws + OFF_VT + (size_t)bh * HDIM * SEQ;

  // Q as B-operand (cols=queries)
  bf16x8 bq[2][2];
#pragma unroll
  for (int m = 0; m < 2; m++) {
    const bf16* qrow = Q + (qw + m * 16 + lq) * HDIM;
    bq[m][0] = ld8(qrow + quad * 8);
    bq[m][1] = ld8(qrow + 32 + quad * 8);
  }

  f32x4 o[2][4];   // O^T accumulators
  float mm[2], ll[2];
#pragma unroll
  for (int m = 0; m < 2; m++) {
    mm[m] = -__builtin_inff(); ll[m] = 0.f;
#pragma unroll
    for (int c = 0; c < 4; c++) o[m][c] = (f32x4){0.f, 0.f, 0.f, 0.f};
  }

  int kend = causal ? (qw + 31) : (SEQ - 1);
  for (int k0 = 0; k0 <= kend; k0 += 64) {
    // ---- S^T: K rows as A-operand, transient per t-subtile
    f32x4 st[2][4];
#pragma unroll
    for (int t = 0; t < 4; t++) {
      const bf16* kr = K + (k0 + t * 16 + lq) * HDIM;
      bf16x8 a0 = ld8(kr + quad * 8);
      bf16x8 a1 = ld8(kr + 32 + quad * 8);
#pragma unroll
      for (int m = 0; m < 2; m++) {
        f32x4 z = {0.f, 0.f, 0.f, 0.f};
        z = __builtin_amdgcn_mfma_f32_16x16x32_bf16(a0, bq[m][0], z, 0, 0, 0);
        z = __builtin_amdgcn_mfma_f32_16x16x32_bf16(a1, bq[m][1], z, 0, 0, 0);
        st[m][t] = z;
      }
    }
    bool needmask = causal && (k0 + 63 > qw);
    float al2[2];
#pragma unroll
    for (int m = 0; m < 2; m++) {
      if (needmask) {
        int qrel = qw + m * 16 + lq - k0 - quad * 4;  // key t*16+r masked if > qrel
#pragma unroll
        for (int t = 0; t < 4; t++)
#pragma unroll
          for (int r = 0; r < 4; r++)
            if (t * 16 + r > qrel) st[m][t][r] = MASKVAL;
      }
      // in-lane max over 16 (ILP tree) + 2 cross-quad shuffles
      float x0 = fmaxf(fmaxf(st[m][0][0], st[m][0][1]), fmaxf(st[m][0][2], st[m][0][3]));
      float x1 = fmaxf(fmaxf(st[m][1][0], st[m][1][1]), fmaxf(st[m][1][2], st[m][1][3]));
      float x2 = fmaxf(fmaxf(st[m][2][0], st[m][2][1]), fmaxf(st[m][2][2], st[m][2][3]));
      float x3 = fmaxf(fmaxf(st[m][3][0], st[m][3][1]), fmaxf(st[m][3][2], st[m][3][3]));
      float mx = fmaxf(fmaxf(x0, x1), fmaxf(x2, x3));
      mx = fmaxf(mx, __shfl_xor(mx, 16));
      mx = fmaxf(mx, __shfl_xor(mx, 32));
      float mn = fmaxf(mm[m], mx);
      float al = exp2f((mm[m] - mn) * SSCALE);
      float mnS = mn * SSCALE;
      float sum = 0.f;
#pragma unroll
      for (int t = 0; t < 4; t++) {        // fused exp + sum + pack + LDS write
        float e0 = exp2f(fmaf(st[m][t][0], SSCALE, -mnS));
        float e1 = exp2f(fmaf(st[m][t][1], SSCALE, -mnS));
        float e2 = exp2f(fmaf(st[m][t][2], SSCALE, -mnS));
        float e3 = exp2f(fmaf(st[m][t][3], SSCALE, -mnS));
        sum += (e0 + e1) + (e2 + e3);
        bf16x4 pk = {(bf16)e0, (bf16)e1, (bf16)e2, (bf16)e3};
        *reinterpret_cast<bf16x4*>(&Pl[m * 16 * 72 + lq * 72 + t * 16 + quad * 4]) = pk;
      }
      sum += __shfl_xor(sum, 16);
      sum += __shfl_xor(sum, 32);
      ll[m] = ll[m] * al + sum;
      mm[m] = mn;
      al2[m] = al;
    }
#pragma unroll
    for (int m = 0; m < 2; m++)
#pragma unroll
      for (int c = 0; c < 4; c++)
#pragma unroll
        for (int r = 0; r < 4; r++) o[m][c][r] *= al2[m];
    // ---- PV: P^T from per-wave LDS as B-operand; V^T rows as A (transient)
    bf16x8 bp[2][2];
#pragma unroll
    for (int m = 0; m < 2; m++) {
      bp[m][0] = ld8(&Pl[m * 16 * 72 + lq * 72 + quad * 8]);
      bp[m][1] = ld8(&Pl[m * 16 * 72 + lq * 72 + 32 + quad * 8]);
    }
#pragma unroll
    for (int c = 0; c < 4; c++) {
      const bf16* vr = VT + (c * 16 + lq) * SEQ + k0;
      bf16x8 av0 = ld8(vr + quad * 8);
      bf16x8 av1 = ld8(vr + 32 + quad * 8);
#pragma unroll
      for (int m = 0; m < 2; m++) {
        o[m][c] = __builtin_amdgcn_mfma_f32_16x16x32_bf16(av0, bp[m][0], o[m][c], 0, 0, 0);
        o[m][c] = __builtin_amdgcn_mfma_f32_16x16x32_bf16(av1, bp[m][1], o[m][c], 0, 0, 0);
      }
    }
  }
  // ---- epilogue: O^T -> attn[B,S,H*D]; d is the reg dim -> bf16x4 stores
  bf16* ar = ws + OFF_ATT;
  int b = bh >> 4, h = bh & 15;
#pragma unroll
  for (int m = 0; m < 2; m++) {
    float inv = 1.0f / ll[m];
    size_t rowoff = ((size_t)(b * SEQ + qw + m * 16 + lq)) * DINNER + h * HDIM;
#pragma unroll
    for (int c = 0; c < 4; c++) {
      bf16x4 ov = {(bf16)(o[m][c][0] * inv), (bf16)(o[m][c][1] * inv),
                   (bf16)(o[m][c][2] * inv), (bf16)(o[m][c][3] * inv)};
      *reinterpret_cast<bf16x4*>(&ar[rowoff + c * 16 + quad * 4]) = ov;
    }
  }
}

// ---------------- kernel 4: output projection, 4-wave split-K --------------
__global__ __launch_bounds__(256) void oproj_kernel(const bf16* __restrict__ ws,
                                                    const int* __restrict__ flag,
                                                    void* __restrict__ outp) {
  __shared__ __align__(16) float red[3 * 64 * 16];  // 12 KB
  int isbf = *flag;
  int tt = blockIdx.x;
  int w = threadIdx.x >> 6;
  int lane = threadIdx.x & 63;
  int lq = lane & 15, quad = lane >> 4;
  const bf16* A = ws + OFF_ATT + (size_t)(tt * 16 + lq) * DINNER;
  const bf16* WoT = ws + OFF_WOT;
  f32x4 acc[4];
#pragma unroll
  for (int c = 0; c < 4; c++) acc[c] = (f32x4){0.f, 0.f, 0.f, 0.f};
  int kbeg = w * 256;
  for (int k0 = kbeg; k0 < kbeg + 256; k0 += 32) {
    bf16x8 a = ld8(A + k0 + quad * 8);
#pragma unroll
    for (int c = 0; c < 4; c++) {
      bf16x8 b = ld8(WoT + (size_t)(c * 16 + lq) * DINNER + k0 + quad * 8);
      acc[c] = __builtin_amdgcn_mfma_f32_16x16x32_bf16(a, b, acc[c], 0, 0, 0);
    }
  }
  if (w > 0) {
#pragma unroll
    for (int c = 0; c < 4; c++)
      *reinterpret_cast<f32x4*>(&red[(((w - 1) * 64 + lane) * 4 + c) * 4]) = acc[c];
  }
  __syncthreads();
  if (w == 0) {
#pragma unroll
    for (int j = 0; j < 3; j++)
#pragma unroll
      for (int c = 0; c < 4; c++)
        acc[c] += *reinterpret_cast<f32x4*>(&red[((j * 64 + lane) * 4 + c) * 4]);
#pragma unroll
    for (int c = 0; c < 4; c++) {
      float bv = (float)ws[OFF_BO + c * 16 + lq];
#pragma unroll
      for (int r = 0; r < 4; r++) {
        int t = tt * 16 + quad * 4 + r;
        float v = acc[c][r] + bv;
        size_t oo = (size_t)t * HDIM + c * 16 + lq;
        if (isbf) ((bf16*)outp)[oo] = (bf16)v;
        else      ((float*)outp)[oo] = v;
      }
    }
  }
}

extern "C" void kernel_launch(void* const* d_in, const int* in_sizes, int n_in,
                              void* d_out, int out_size, void* d_ws, size_t ws_size,
                              hipStream_t stream) {
  const void* x  = d_in[0];
  const void* Wq = d_in[1];
  const void* Wk = d_in[2];
  const void* Wv = d_in[3];
  const void* Wo = d_in[4];
  const void* bo = d_in[5];
  const int* cm  = (const int*)d_in[6];
  bf16* ws = (bf16*)d_ws;
  int* flag = (int*)d_ws;

  hipLaunchKernelGGL(detect_kernel, dim3(1), dim3(64), 0, stream,
                     (const unsigned short*)x, flag);
  hipLaunchKernelGGL(prep_kernel, dim3(256, 13), dim3(256), 0, stream,
                     x, Wq, Wk, Wv, Wo, bo, flag, ws);
  hipLaunchKernelGGL(qkv_kernel, dim3(128, 4, 3), dim3(256), 0, stream, ws);
  hipLaunchKernelGGL(flash_kernel, dim3(4096), dim3(64), 0, stream, cm, ws);
  hipLaunchKernelGGL(oproj_kernel, dim3(512), dim3(256), 0, stream, ws, flag, d_out);
}